// Round 4
// baseline (2217.835 us; speedup 1.0000x reference)
//
#include <hip/hip_runtime.h>

#define TT 512   // sequence length
#define BB 64    // batch
#define HH 128   // hidden
#define G4 512   // 4*H
#define PF 4     // prefetch ring depth (even, divides TT)

// ---------------- pre-GEMM: C[m,g] = sum_k A[m,k]W[g,k] + b0[g] + b1[g] ----------------
// BK=32, register-prefetched staging, coalesced loads. grid (M/128, 4), 256 thr.
template<int K>
__global__ __launch_bounds__(256) void gemm_pre(
    const float* __restrict__ A, const float* __restrict__ W,
    const float* __restrict__ b0, const float* __restrict__ b1,
    float* __restrict__ C)
{
    __shared__ float As[32][132];
    __shared__ float Ws[32][132];
    const int bm = blockIdx.x * 128;
    const int bn = blockIdx.y * 128;
    const int tid = threadIdx.x;
    const int tx = tid & 15;        // n micro
    const int ty = tid >> 4;        // m micro

    // staging map: float4 id = q*256+tid -> row = id>>3, col = (id&7)*4
    float4 pa[4], pw[4];
    #pragma unroll
    for (int q = 0; q < 4; ++q) {
        int id = q * 256 + tid;
        int r = id >> 3, cl = (id & 7) * 4;
        pa[q] = *(const float4*)&A[(size_t)(bm + r) * K + cl];
        pw[q] = *(const float4*)&W[(size_t)(bn + r) * K + cl];
    }

    float acc[8][8];
    #pragma unroll
    for (int i = 0; i < 8; ++i)
        #pragma unroll
        for (int jj = 0; jj < 8; ++jj) acc[i][jj] = 0.f;

    for (int k0 = 0; k0 < K; k0 += 32) {
        __syncthreads();
        #pragma unroll
        for (int q = 0; q < 4; ++q) {
            int id = q * 256 + tid;
            int r = id >> 3, cl = (id & 7) * 4;
            As[cl+0][r] = pa[q].x; As[cl+1][r] = pa[q].y;
            As[cl+2][r] = pa[q].z; As[cl+3][r] = pa[q].w;
            Ws[cl+0][r] = pw[q].x; Ws[cl+1][r] = pw[q].y;
            Ws[cl+2][r] = pw[q].z; Ws[cl+3][r] = pw[q].w;
        }
        __syncthreads();
        if (k0 + 32 < K) {
            #pragma unroll
            for (int q = 0; q < 4; ++q) {
                int id = q * 256 + tid;
                int r = id >> 3, cl = (id & 7) * 4;
                pa[q] = *(const float4*)&A[(size_t)(bm + r) * K + k0 + 32 + cl];
                pw[q] = *(const float4*)&W[(size_t)(bn + r) * K + k0 + 32 + cl];
            }
        }
        #pragma unroll
        for (int kk = 0; kk < 32; ++kk) {
            float a[8], w[8];
            *(float4*)&a[0] = *(const float4*)&As[kk][ty*8];
            *(float4*)&a[4] = *(const float4*)&As[kk][ty*8+4];
            *(float4*)&w[0] = *(const float4*)&Ws[kk][tx*8];
            *(float4*)&w[4] = *(const float4*)&Ws[kk][tx*8+4];
            #pragma unroll
            for (int i = 0; i < 8; ++i)
                #pragma unroll
                for (int jj = 0; jj < 8; ++jj)
                    acc[i][jj] = fmaf(a[i], w[jj], acc[i][jj]);
        }
    }
    #pragma unroll
    for (int i = 0; i < 8; ++i) {
        int m = bm + ty*8 + i;
        #pragma unroll
        for (int jj = 0; jj < 8; jj += 4) {
            int n = bn + tx*8 + jj;
            float4 v;
            v.x = acc[i][jj]   + b0[n]   + b1[n];
            v.y = acc[i][jj+1] + b0[n+1] + b1[n+1];
            v.z = acc[i][jj+2] + b0[n+2] + b1[n+2];
            v.w = acc[i][jj+3] + b0[n+3] + b1[n+3];
            *(float4*)&C[(size_t)m * G4 + n] = v;
        }
    }
}

// ---------------- scalar LSTM scan v4: 128 blocks, 256 thr (4 waves) ----------------
// Lane (w,l): cell j = w*32 + (l&31). half = l>>5.
//   half0 owns gate rows {j (i), 2H+j (g)}; half1 owns {H+j (f), 3H+j (o)}.
// Each lane: 2 dot products vs h (LDS broadcast), own-gate activations,
// 2 shfl_xor(32) to pass sf,so to half0 partner which owns c and writes h.
__global__ __launch_bounds__(256, 1) void lstm_scan_v4(
    const float* __restrict__ pre_f, const float* __restrict__ pre_b,
    const float* __restrict__ whh_f, const float* __restrict__ whh_b,
    float* __restrict__ out)
{
    const int dir = blockIdx.x >> 6;
    const int b   = blockIdx.x & 63;
    const float* __restrict__ pre  = dir ? pre_b : pre_f;
    const float* __restrict__ w_hh = dir ? whh_b : whh_f;

    const int tid  = threadIdx.x;
    const int w    = tid >> 6;
    const int l    = tid & 63;
    const int half = l >> 5;
    const int li   = l & 31;
    const int j    = w * 32 + li;           // cell 0..127
    const int gA   = half * HH + j;         // i-row or f-row
    const int gB   = (2 + half) * HH + j;   // g-row or o-row

    __shared__ float h_lds[2][HH];

    // pin both gate rows in registers (static indices only)
    float wA[HH], wB[HH];
    #pragma unroll
    for (int k = 0; k < HH; k += 4) {
        *(float4*)&wA[k] = *(const float4*)&w_hh[(size_t)gA * HH + k];
        *(float4*)&wB[k] = *(const float4*)&w_hh[(size_t)gB * HH + k];
    }

    if (tid < HH) { h_lds[0][tid] = 0.f; h_lds[1][tid] = 0.f; }

    const size_t baseA = (size_t)b * TT * G4 + gA;
    const size_t baseB = (size_t)b * TT * G4 + gB;
    float pfA[PF], pfB[PF];
    #pragma unroll
    for (int u = 0; u < PF; ++u) {
        int tau = dir ? (TT - 1 - u) : u;
        pfA[u] = pre[baseA + (size_t)tau * G4];
        pfB[u] = pre[baseB + (size_t)tau * G4];
    }

    float c = 0.f;
    const float ASIG = -1.4426950408889634f;  // -log2(e)
    const float ATAN =  2.8853900817779268f;  // 2*log2(e)
    const float aB   = half ? ASIG : ATAN;    // half0's B-gate is tanh(g)

    float* outp = out + (size_t)b * TT * (2*HH) + dir * HH + j
                + (dir ? (size_t)(TT - 1) * (2*HH) : (size_t)0);
    const int ostep = dir ? -(2*HH) : (2*HH);

    __syncthreads();

    for (int s0 = 0; s0 < TT; s0 += PF) {
        #pragma unroll
        for (int u = 0; u < PF; ++u) {
            const int s = s0 + u;
            const int cur = u & 1;           // s0 multiple of PF(even) -> parity(s)=parity(u)
            const float* hb = h_lds[cur];

            float a0=0.f,a1=0.f,a2=0.f,a3=0.f, c0=0.f,c1=0.f,c2=0.f,c3=0.f;
            #pragma unroll
            for (int k = 0; k < HH; k += 4) {
                float4 h4 = *(const float4*)&hb[k];   // wave-uniform broadcast
                a0 = fmaf(wA[k],   h4.x, a0);
                a1 = fmaf(wA[k+1], h4.y, a1);
                a2 = fmaf(wA[k+2], h4.z, a2);
                a3 = fmaf(wA[k+3], h4.w, a3);
                c0 = fmaf(wB[k],   h4.x, c0);
                c1 = fmaf(wB[k+1], h4.y, c1);
                c2 = fmaf(wB[k+2], h4.z, c2);
                c3 = fmaf(wB[k+3], h4.w, c3);
            }
            float gateA = pfA[u] + ((a0 + a1) + (a2 + a3));
            float gateB = pfB[u] + ((c0 + c1) + (c2 + c3));

            // ring refill (clamped, branch-free)
            {
                int sn = s + PF;
                int taun = dir ? (TT - 1 - sn) : sn;
                taun = taun < 0 ? 0 : (taun > TT - 1 ? TT - 1 : taun);
                pfA[u] = pre[baseA + (size_t)taun * G4];
                pfB[u] = pre[baseB + (size_t)taun * G4];
            }

            // own-gate activations
            float eA = __builtin_amdgcn_exp2f(ASIG * gateA);
            float vA = __builtin_amdgcn_rcpf(1.f + eA);            // si or sf
            float eB = __builtin_amdgcn_exp2f(aB * gateB);
            float rB = __builtin_amdgcn_rcpf(1.f + eB);
            float vB = half ? rB : (1.f - 2.f * rB);               // so or tg

            // pass (sf, so) from half1 to half0 partner
            float sfx = __shfl(vA, l ^ 32);
            float sox = __shfl(vB, l ^ 32);

            if (half == 0) {
                c = fmaf(sfx, c, vA * vB);                          // f*c + i*g
                float e2 = __builtin_amdgcn_exp2f(ATAN * c);
                float r2 = __builtin_amdgcn_rcpf(1.f + e2);
                float h  = sox * (1.f - 2.f * r2);                  // o * tanh(c)
                h_lds[cur ^ 1][j] = h;
                outp[0] = h;
            }
            outp += ostep;
            __syncthreads();
        }
    }
}

// ---------------- FC ----------------
__global__ __launch_bounds__(256) void fc_kernel(
    const float* __restrict__ h2, const float* __restrict__ w_fc,
    const float* __restrict__ b_fc, float* __restrict__ out)
{
    int idx = blockIdx.x * 256 + threadIdx.x;
    int m = idx >> 6;
    int n = idx & 63;
    const float4* hr = (const float4*)(h2 + (size_t)m * 256);
    const float4* wr = (const float4*)(w_fc + (size_t)n * 256);
    float acc = 0.f;
    #pragma unroll 8
    for (int k = 0; k < 64; ++k) {
        float4 a = hr[k];
        float4 wv = wr[k];
        acc += a.x*wv.x + a.y*wv.y + a.z*wv.z + a.w*wv.w;
    }
    out[idx] = acc + b_fc[n];
}

extern "C" void kernel_launch(void* const* d_in, const int* in_sizes, int n_in,
                              void* d_out, int out_size, void* d_ws, size_t ws_size,
                              hipStream_t stream) {
    const float* x        = (const float*)d_in[0];
    const float* w_ih_l0  = (const float*)d_in[1];
    const float* w_hh_l0  = (const float*)d_in[2];
    const float* b_ih_l0  = (const float*)d_in[3];
    const float* b_hh_l0  = (const float*)d_in[4];
    const float* w_ih_l0r = (const float*)d_in[5];
    const float* w_hh_l0r = (const float*)d_in[6];
    const float* b_ih_l0r = (const float*)d_in[7];
    const float* b_hh_l0r = (const float*)d_in[8];
    const float* w_ih_l1  = (const float*)d_in[9];
    const float* w_hh_l1  = (const float*)d_in[10];
    const float* b_ih_l1  = (const float*)d_in[11];
    const float* b_hh_l1  = (const float*)d_in[12];
    const float* w_ih_l1r = (const float*)d_in[13];
    const float* w_hh_l1r = (const float*)d_in[14];
    const float* b_ih_l1r = (const float*)d_in[15];
    const float* b_hh_l1r = (const float*)d_in[16];
    const float* w_fc     = (const float*)d_in[17];
    const float* b_fc     = (const float*)d_in[18];

    float* ws    = (float*)d_ws;
    float* pre_f = ws;                       // 16,777,216 floats
    float* pre_b = ws + 16777216;            // 16,777,216 floats
    float* out0  = ws + 2 * 16777216;        // 8,388,608 floats
    float* out1  = out0 + 8388608;           // 8,388,608 floats

    dim3 gg(256, 4);

    // Layer 0
    gemm_pre<64><<<gg, 256, 0, stream>>>(x, w_ih_l0,  b_ih_l0,  b_hh_l0,  pre_f);
    gemm_pre<64><<<gg, 256, 0, stream>>>(x, w_ih_l0r, b_ih_l0r, b_hh_l0r, pre_b);
    lstm_scan_v4<<<128, 256, 0, stream>>>(pre_f, pre_b, w_hh_l0, w_hh_l0r, out0);

    // Layer 1
    gemm_pre<256><<<gg, 256, 0, stream>>>(out0, w_ih_l1,  b_ih_l1,  b_hh_l1,  pre_f);
    gemm_pre<256><<<gg, 256, 0, stream>>>(out0, w_ih_l1r, b_ih_l1r, b_hh_l1r, pre_b);
    lstm_scan_v4<<<128, 256, 0, stream>>>(pre_f, pre_b, w_hh_l1, w_hh_l1r, out1);

    // FC
    fc_kernel<<<(BB*TT*64)/256, 256, 0, stream>>>(out1, w_fc, b_fc, (float*)d_out);
}

// Round 5
// 1025.742 us; speedup vs baseline: 2.1622x; 2.1622x over previous
//
#include <hip/hip_runtime.h>

#define TT 512   // sequence length
#define BB 64    // batch
#define HH 128   // hidden
#define G4 512   // 4*H
#define PF 8     // prefetch ring depth (even, divides TT)

typedef short bf16x8 __attribute__((ext_vector_type(8)));
typedef short s16x4  __attribute__((ext_vector_type(4)));
typedef float f32x4  __attribute__((ext_vector_type(4)));
typedef _Float16 h2f __attribute__((ext_vector_type(2)));
typedef _Float16 h8f __attribute__((ext_vector_type(8)));

__device__ __forceinline__ unsigned short f2bf(float x) {
    unsigned u = __float_as_uint(x);
    u += 0x7fff + ((u >> 16) & 1);           // RNE
    return (unsigned short)(u >> 16);
}
__device__ __forceinline__ float bf2f(unsigned short h) {
    return __uint_as_float(((unsigned)h) << 16);
}

__device__ __forceinline__ float fdot2_(h2f a, h2f b, float c) {
#if __has_builtin(__builtin_amdgcn_fdot2)
    return __builtin_amdgcn_fdot2(a, b, c, false);
#else
    return c + (float)a[0] * (float)b[0] + (float)a[1] * (float)b[1];
#endif
}

// ---------------- MFMA pre-GEMM ----------------
// C[m,n] = sum_k A[m,k]W[n,k] + b0[n] + b1[n], fp32 in/out.
// bf16 hi/lo split, 3-term product (hi*hi + hi*lo + lo*hi) => fp32-equivalent.
// Tile 128x128, KC=32, 4 waves; wave (wr,wc) owns a 64x64 quadrant (4x4 MFMA tiles).
template<int K>
__global__ __launch_bounds__(256) void gemm_mfma(
    const float* __restrict__ A, const float* __restrict__ W,
    const float* __restrict__ b0, const float* __restrict__ b1,
    float* __restrict__ C)
{
    constexpr int NC  = K / 32;
    constexpr int LDA = 40;                  // shorts per staged row (32 + 8 pad, keeps 16B align)
    __shared__ short Ahi[128 * LDA], Alo[128 * LDA];
    __shared__ short Whi[128 * LDA], Wlo[128 * LDA];

    const int bm  = blockIdx.x * 128;
    const int bn  = blockIdx.y * 128;
    const int tid = threadIdx.x;
    const int wv  = tid >> 6;        // wave 0..3
    const int l   = tid & 63;
    const int jl  = l & 15;
    const int rg  = l >> 4;          // 0..3
    const int wr  = wv >> 1;         // row quadrant
    const int wc  = wv & 1;          // col quadrant

    const int sr = tid >> 1;         // staging row 0..127
    const int sc = (tid & 1) * 16;   // staging col base (floats)

    const float* Ap = A + (size_t)(bm + sr) * K + sc;
    const float* Wp = W + (size_t)(bn + sr) * K + sc;

    f32x4 acc[4][4];
    #pragma unroll
    for (int i = 0; i < 4; ++i)
        #pragma unroll
        for (int j = 0; j < 4; ++j)
            acc[i][j] = (f32x4){0.f, 0.f, 0.f, 0.f};

    float4 pa[4], pw[4];
    #pragma unroll
    for (int q = 0; q < 4; ++q) {
        pa[q] = *(const float4*)(Ap + q * 4);
        pw[q] = *(const float4*)(Wp + q * 4);
    }

    #pragma unroll 1
    for (int c = 0; c < NC; ++c) {
        __syncthreads();                     // prior compute done
        #pragma unroll
        for (int q = 0; q < 4; ++q) {
            float fa[4] = {pa[q].x, pa[q].y, pa[q].z, pa[q].w};
            float fw[4] = {pw[q].x, pw[q].y, pw[q].z, pw[q].w};
            s16x4 ha, la, hw, lw;
            #pragma unroll
            for (int e = 0; e < 4; ++e) {
                unsigned short h = f2bf(fa[e]);
                ha[e] = (short)h;
                la[e] = (short)f2bf(fa[e] - bf2f(h));
                unsigned short g = f2bf(fw[e]);
                hw[e] = (short)g;
                lw[e] = (short)f2bf(fw[e] - bf2f(g));
            }
            int off = sr * LDA + sc + q * 4;
            *(s16x4*)&Ahi[off] = ha;
            *(s16x4*)&Alo[off] = la;
            *(s16x4*)&Whi[off] = hw;
            *(s16x4*)&Wlo[off] = lw;
        }
        __syncthreads();
        if (c + 1 < NC) {                    // prefetch next chunk (overlaps MFMA)
            #pragma unroll
            for (int q = 0; q < 4; ++q) {
                pa[q] = *(const float4*)(Ap + (c + 1) * 32 + q * 4);
                pw[q] = *(const float4*)(Wp + (c + 1) * 32 + q * 4);
            }
        }
        bf16x8 ah[4], al[4], wh[4], wl[4];
        #pragma unroll
        for (int t = 0; t < 4; ++t) {
            int ra = (wr * 64 + t * 16 + jl) * LDA + rg * 8;
            ah[t] = *(const bf16x8*)&Ahi[ra];
            al[t] = *(const bf16x8*)&Alo[ra];
            int rw = (wc * 64 + t * 16 + jl) * LDA + rg * 8;
            wh[t] = *(const bf16x8*)&Whi[rw];
            wl[t] = *(const bf16x8*)&Wlo[rw];
        }
        #pragma unroll
        for (int tm = 0; tm < 4; ++tm)
            #pragma unroll
            for (int tn = 0; tn < 4; ++tn) {
                acc[tm][tn] = __builtin_amdgcn_mfma_f32_16x16x32_bf16(ah[tm], wh[tn], acc[tm][tn], 0, 0, 0);
                acc[tm][tn] = __builtin_amdgcn_mfma_f32_16x16x32_bf16(ah[tm], wl[tn], acc[tm][tn], 0, 0, 0);
                acc[tm][tn] = __builtin_amdgcn_mfma_f32_16x16x32_bf16(al[tm], wh[tn], acc[tm][tn], 0, 0, 0);
            }
    }

    // epilogue: C layout col=lane&15 (n), row=(lane>>4)*4+r (m)  [HW-verified in R2]
    #pragma unroll
    for (int tn = 0; tn < 4; ++tn) {
        int n = bn + wc * 64 + tn * 16 + jl;
        float bias = b0[n] + b1[n];
        #pragma unroll
        for (int tm = 0; tm < 4; ++tm) {
            int m = bm + wr * 64 + tm * 16 + rg * 4;
            #pragma unroll
            for (int r = 0; r < 4; ++r)
                C[(size_t)(m + r) * G4 + n] = acc[tm][tn][r] + bias;
        }
    }
}

// ---------------- scalar LSTM scan v5: v3 structure + fp16 h + dot2 ----------------
// 128 blocks = 2dir x 64batch, 512 thr (8 waves). Lane: cell j = w*16+(l&15),
// gate type tt = l>>4. w_hh row as 64 packed-fp16 pairs in VGPRs. h packed fp16
// in LDS (16 uniform b128 reads/wave), double-buffered, 1 barrier/step.
__global__ __launch_bounds__(512) void lstm_scan_v5(
    const float* __restrict__ pre_f, const float* __restrict__ pre_b,
    const float* __restrict__ whh_f, const float* __restrict__ whh_b,
    float* __restrict__ out)
{
    const int dir = blockIdx.x >> 6;
    const int b   = blockIdx.x & 63;
    const float* __restrict__ pre  = dir ? pre_b : pre_f;
    const float* __restrict__ w_hh = dir ? whh_b : whh_f;

    const int tid = threadIdx.x;
    const int w   = tid >> 6;
    const int l   = tid & 63;
    const int jl  = l & 15;
    const int tt  = l >> 4;          // gate type (i,f,g,o)
    const int j   = w * 16 + jl;     // cell index 0..127
    const int g   = tt * HH + j;     // gate row 0..511

    __shared__ _Float16 h_lds[2][HH];

    // pin gate row as packed fp16 (64 dword-regs)
    h2f wv[64];
    #pragma unroll
    for (int k = 0; k < HH; k += 4) {
        float4 f = *(const float4*)&w_hh[(size_t)g * HH + k];
        wv[k / 2]     = (h2f){(_Float16)f.x, (_Float16)f.y};
        wv[k / 2 + 1] = (h2f){(_Float16)f.z, (_Float16)f.w};
    }

    if (tid < 2 * HH) ((_Float16*)h_lds)[tid] = (_Float16)0.f;

    const size_t base = (size_t)b * TT * G4 + g;
    float pf[PF];
    #pragma unroll
    for (int u = 0; u < PF; ++u) {
        int tau = dir ? (TT - 1 - u) : u;
        pf[u] = pre[base + (size_t)tau * G4];
    }

    float c = 0.f;
    const float ASIG = -1.4426950408889634f;  // -log2(e)
    const float ATAN =  2.8853900817779268f;  // 2*log2(e)
    const float aa = (tt == 2) ? ATAN : ASIG;

    __syncthreads();

    for (int s0 = 0; s0 < TT; s0 += PF) {
        #pragma unroll
        for (int u = 0; u < PF; ++u) {
            const int s = s0 + u;
            const int cur = u & 1;            // parity(s) == parity(u)

            float a0 = 0.f, a1 = 0.f, a2 = 0.f, a3 = 0.f;
            #pragma unroll
            for (int k = 0; k < HH; k += 8) {
                union { h8f v; h2f p[4]; } hu;
                hu.v = *(const h8f*)&h_lds[cur][k];   // uniform broadcast b128
                a0 = fdot2_(wv[k / 2 + 0], hu.p[0], a0);
                a1 = fdot2_(wv[k / 2 + 1], hu.p[1], a1);
                a2 = fdot2_(wv[k / 2 + 2], hu.p[2], a2);
                a3 = fdot2_(wv[k / 2 + 3], hu.p[3], a3);
            }
            float gate = pf[u] + ((a0 + a1) + (a2 + a3));

            // ring refill (clamped, branch-free)
            {
                int sn = s + PF;
                int taun = dir ? (TT - 1 - sn) : sn;
                taun = taun < 0 ? 0 : (taun > TT - 1 ? TT - 1 : taun);
                pf[u] = pre[base + (size_t)taun * G4];
            }

            // own-gate activation: sigmoid (i,f,o) / tanh (g)
            float e = __builtin_amdgcn_exp2f(aa * gate);
            float r = __builtin_amdgcn_rcpf(1.f + e);
            float v = (tt == 2) ? (1.f - 2.f * r) : r;

            // gather cell's sf, tg, so to the tt==0 lane
            float sf = __shfl(v, jl + 16);
            float tg = __shfl(v, jl + 32);
            float so = __shfl(v, jl + 48);

            if (tt == 0) {
                c = fmaf(sf, c, v * tg);
                float e2 = __builtin_amdgcn_exp2f(ATAN * c);
                float r2 = __builtin_amdgcn_rcpf(1.f + e2);
                float h  = so * (1.f - 2.f * r2);
                h_lds[cur ^ 1][j] = (_Float16)h;
                int tau = dir ? (TT - 1 - s) : s;
                out[((size_t)b * TT + tau) * (2 * HH) + dir * HH + j] = h;
            }
            __syncthreads();
        }
    }
}

// ---------------- FC ----------------
__global__ __launch_bounds__(256) void fc_kernel(
    const float* __restrict__ h2, const float* __restrict__ w_fc,
    const float* __restrict__ b_fc, float* __restrict__ out)
{
    int idx = blockIdx.x * 256 + threadIdx.x;
    int m = idx >> 6;
    int n = idx & 63;
    const float4* hr = (const float4*)(h2 + (size_t)m * 256);
    const float4* wr = (const float4*)(w_fc + (size_t)n * 256);
    float acc = 0.f;
    #pragma unroll 8
    for (int k = 0; k < 64; ++k) {
        float4 a = hr[k];
        float4 wv = wr[k];
        acc += a.x * wv.x + a.y * wv.y + a.z * wv.z + a.w * wv.w;
    }
    out[idx] = acc + b_fc[n];
}

extern "C" void kernel_launch(void* const* d_in, const int* in_sizes, int n_in,
                              void* d_out, int out_size, void* d_ws, size_t ws_size,
                              hipStream_t stream) {
    const float* x        = (const float*)d_in[0];
    const float* w_ih_l0  = (const float*)d_in[1];
    const float* w_hh_l0  = (const float*)d_in[2];
    const float* b_ih_l0  = (const float*)d_in[3];
    const float* b_hh_l0  = (const float*)d_in[4];
    const float* w_ih_l0r = (const float*)d_in[5];
    const float* w_hh_l0r = (const float*)d_in[6];
    const float* b_ih_l0r = (const float*)d_in[7];
    const float* b_hh_l0r = (const float*)d_in[8];
    const float* w_ih_l1  = (const float*)d_in[9];
    const float* w_hh_l1  = (const float*)d_in[10];
    const float* b_ih_l1  = (const float*)d_in[11];
    const float* b_hh_l1  = (const float*)d_in[12];
    const float* w_ih_l1r = (const float*)d_in[13];
    const float* w_hh_l1r = (const float*)d_in[14];
    const float* b_ih_l1r = (const float*)d_in[15];
    const float* b_hh_l1r = (const float*)d_in[16];
    const float* w_fc     = (const float*)d_in[17];
    const float* b_fc     = (const float*)d_in[18];

    float* ws    = (float*)d_ws;
    float* pre_f = ws;                       // 16,777,216 floats
    float* pre_b = ws + 16777216;            // 16,777,216 floats
    float* out0  = ws + 2 * 16777216;        // 8,388,608 floats
    float* out1  = out0 + 8388608;           // 8,388,608 floats

    dim3 gg(256, 4);  // M/128 x 512/128

    // Layer 0
    gemm_mfma<64><<<gg, 256, 0, stream>>>(x, w_ih_l0,  b_ih_l0,  b_hh_l0,  pre_f);
    gemm_mfma<64><<<gg, 256, 0, stream>>>(x, w_ih_l0r, b_ih_l0r, b_hh_l0r, pre_b);
    lstm_scan_v5<<<128, 512, 0, stream>>>(pre_f, pre_b, w_hh_l0, w_hh_l0r, out0);

    // Layer 1
    gemm_mfma<256><<<gg, 256, 0, stream>>>(out0, w_ih_l1,  b_ih_l1,  b_hh_l1,  pre_f);
    gemm_mfma<256><<<gg, 256, 0, stream>>>(out0, w_ih_l1r, b_ih_l1r, b_hh_l1r, pre_b);
    lstm_scan_v5<<<128, 512, 0, stream>>>(pre_f, pre_b, w_hh_l1, w_hh_l1r, out1);

    // FC
    fc_kernel<<<(BB * TT * 64) / 256, 256, 0, stream>>>(out1, w_fc, b_fc, (float*)d_out);
}

// Round 6
// 967.953 us; speedup vs baseline: 2.2913x; 1.0597x over previous
//
#include <hip/hip_runtime.h>

#define TT 512   // sequence length
#define BB 64    // batch
#define HH 128   // hidden
#define G4 512   // 4*H
#define PF 8     // prefetch ring depth (even, divides TT)

typedef short bf16x8 __attribute__((ext_vector_type(8)));
typedef short s16x4  __attribute__((ext_vector_type(4)));
typedef float f32x4  __attribute__((ext_vector_type(4)));
typedef _Float16 h2f __attribute__((ext_vector_type(2)));
typedef _Float16 h8f __attribute__((ext_vector_type(8)));

__device__ __forceinline__ unsigned short f2bf(float x) {
    unsigned u = __float_as_uint(x);
    u += 0x7fff + ((u >> 16) & 1);           // RNE
    return (unsigned short)(u >> 16);
}
__device__ __forceinline__ float bf2f(unsigned short h) {
    return __uint_as_float(((unsigned)h) << 16);
}
__device__ __forceinline__ float fdot2_(h2f a, h2f b, float c) {
#if __has_builtin(__builtin_amdgcn_fdot2)
    return __builtin_amdgcn_fdot2(a, b, c, false);
#else
    return c + (float)a[0] * (float)b[0] + (float)a[1] * (float)b[1];
#endif
}

// ---------------- fp32 -> bf16 hi/lo split (memory-bound) ----------------
__global__ __launch_bounds__(256) void convert_hilo(
    const float4* __restrict__ src, s16x4* __restrict__ hi,
    s16x4* __restrict__ lo, int n4)
{
    for (int i = blockIdx.x * 256 + threadIdx.x; i < n4; i += gridDim.x * 256) {
        float4 f = src[i];
        float fa[4] = {f.x, f.y, f.z, f.w};
        s16x4 h, l;
        #pragma unroll
        for (int e = 0; e < 4; ++e) {
            unsigned short hh = f2bf(fa[e]);
            h[e] = (short)hh;
            l[e] = (short)f2bf(fa[e] - bf2f(hh));
        }
        hi[i] = h;
        lo[i] = l;
    }
}

// ---------------- MFMA pre-GEMM v2: A pre-split bf16, W converted in-kernel ----
// C[m,n] = sum_k A[m,k]W[n,k] + b0[n] + b1[n].
// 3-term hi/lo product => fp32-equivalent. Tile 128x128, KC=32, 4 waves.
template<int K>
__global__ __launch_bounds__(256) void gemm_mfma2(
    const short* __restrict__ Ahi, const short* __restrict__ Alo,
    const float* __restrict__ W,
    const float* __restrict__ b0, const float* __restrict__ b1,
    float* __restrict__ C)
{
    constexpr int NC  = K / 32;
    constexpr int LDA = 40;                  // shorts per staged row (32 + 8 pad)
    __shared__ short Ahi_s[128 * LDA], Alo_s[128 * LDA];
    __shared__ short Whi_s[128 * LDA], Wlo_s[128 * LDA];

    const int bm  = blockIdx.x * 128;
    const int bn  = blockIdx.y * 128;
    const int tid = threadIdx.x;
    const int wv  = tid >> 6;
    const int l   = tid & 63;
    const int jl  = l & 15;
    const int rg  = l >> 4;
    const int wr  = wv >> 1;
    const int wc  = wv & 1;

    const int sr = tid >> 1;         // staging row 0..127
    const int sc = (tid & 1) * 16;   // staging col base (elements of 32)

    const short* Aph = Ahi + (size_t)(bm + sr) * K + sc;
    const short* Apl = Alo + (size_t)(bm + sr) * K + sc;
    const float* Wp  = W   + (size_t)(bn + sr) * K + sc;

    f32x4 acc[4][4];
    #pragma unroll
    for (int i = 0; i < 4; ++i)
        #pragma unroll
        for (int j = 0; j < 4; ++j)
            acc[i][j] = (f32x4){0.f, 0.f, 0.f, 0.f};

    bf16x8 pah[2], pal[2];
    float4 pw[4];
    pah[0] = *(const bf16x8*)(Aph);
    pah[1] = *(const bf16x8*)(Aph + 8);
    pal[0] = *(const bf16x8*)(Apl);
    pal[1] = *(const bf16x8*)(Apl + 8);
    #pragma unroll
    for (int q = 0; q < 4; ++q) pw[q] = *(const float4*)(Wp + q * 4);

    #pragma unroll 1
    for (int c = 0; c < NC; ++c) {
        __syncthreads();                     // prior MFMA reads done
        {
            int off = sr * LDA + sc;
            *(bf16x8*)&Ahi_s[off]     = pah[0];
            *(bf16x8*)&Ahi_s[off + 8] = pah[1];
            *(bf16x8*)&Alo_s[off]     = pal[0];
            *(bf16x8*)&Alo_s[off + 8] = pal[1];
            #pragma unroll
            for (int q = 0; q < 4; ++q) {
                float fw[4] = {pw[q].x, pw[q].y, pw[q].z, pw[q].w};
                s16x4 h, lo4;
                #pragma unroll
                for (int e = 0; e < 4; ++e) {
                    unsigned short hh = f2bf(fw[e]);
                    h[e]   = (short)hh;
                    lo4[e] = (short)f2bf(fw[e] - bf2f(hh));
                }
                *(s16x4*)&Whi_s[off + q * 4] = h;
                *(s16x4*)&Wlo_s[off + q * 4] = lo4;
            }
        }
        __syncthreads();
        if (c + 1 < NC) {
            pah[0] = *(const bf16x8*)(Aph + (c + 1) * 32);
            pah[1] = *(const bf16x8*)(Aph + (c + 1) * 32 + 8);
            pal[0] = *(const bf16x8*)(Apl + (c + 1) * 32);
            pal[1] = *(const bf16x8*)(Apl + (c + 1) * 32 + 8);
            #pragma unroll
            for (int q = 0; q < 4; ++q)
                pw[q] = *(const float4*)(Wp + (c + 1) * 32 + q * 4);
        }
        bf16x8 ah[4], al[4], wh[4], wl[4];
        #pragma unroll
        for (int t = 0; t < 4; ++t) {
            int ra = (wr * 64 + t * 16 + jl) * LDA + rg * 8;
            ah[t] = *(const bf16x8*)&Ahi_s[ra];
            al[t] = *(const bf16x8*)&Alo_s[ra];
            int rw = (wc * 64 + t * 16 + jl) * LDA + rg * 8;
            wh[t] = *(const bf16x8*)&Whi_s[rw];
            wl[t] = *(const bf16x8*)&Wlo_s[rw];
        }
        #pragma unroll
        for (int tm = 0; tm < 4; ++tm)
            #pragma unroll
            for (int tn = 0; tn < 4; ++tn) {
                acc[tm][tn] = __builtin_amdgcn_mfma_f32_16x16x32_bf16(ah[tm], wh[tn], acc[tm][tn], 0, 0, 0);
                acc[tm][tn] = __builtin_amdgcn_mfma_f32_16x16x32_bf16(ah[tm], wl[tn], acc[tm][tn], 0, 0, 0);
                acc[tm][tn] = __builtin_amdgcn_mfma_f32_16x16x32_bf16(al[tm], wh[tn], acc[tm][tn], 0, 0, 0);
            }
    }

    // epilogue: C layout col=lane&15 (n), row=(lane>>4)*4+r (m)
    #pragma unroll
    for (int tn = 0; tn < 4; ++tn) {
        int n = bn + wc * 64 + tn * 16 + jl;
        float bias = b0[n] + b1[n];
        #pragma unroll
        for (int tm = 0; tm < 4; ++tm) {
            int m = bm + wr * 64 + tm * 16 + rg * 4;
            #pragma unroll
            for (int r = 0; r < 4; ++r)
                C[(size_t)(m + r) * G4 + n] = acc[tm][tn][r] + bias;
        }
    }
}

// ---------------- scalar LSTM scan v6: v5 + quad-DPP gate exchange ----------------
// 128 blocks = 2dir x 64batch, 512 thr (8 waves). Lane l: gate type q = l&3,
// cell j = w*16 + (l>>2). A cell's i,f,g,o sit in one DPP quad -> gate exchange
// via 3 quad_perm rotations (VALU), no LDS shuffles.
__global__ __launch_bounds__(512) void lstm_scan_v6(
    const float* __restrict__ pre_f, const float* __restrict__ pre_b,
    const float* __restrict__ whh_f, const float* __restrict__ whh_b,
    float* __restrict__ out)
{
    const int dir = blockIdx.x >> 6;
    const int b   = blockIdx.x & 63;
    const float* __restrict__ pre  = dir ? pre_b : pre_f;
    const float* __restrict__ w_hh = dir ? whh_b : whh_f;

    const int tid = threadIdx.x;
    const int w   = tid >> 6;
    const int l   = tid & 63;
    const int q   = l & 3;           // gate type (i,f,g,o)
    const int ci  = l >> 2;          // cell-in-wave 0..15
    const int j   = w * 16 + ci;     // cell index 0..127
    const int g   = q * HH + j;      // gate row 0..511

    __shared__ _Float16 h_lds[2][HH];

    // pin gate row as packed fp16 (64 dword-regs)
    h2f wv[64];
    #pragma unroll
    for (int k = 0; k < HH; k += 4) {
        float4 f = *(const float4*)&w_hh[(size_t)g * HH + k];
        wv[k / 2]     = (h2f){(_Float16)f.x, (_Float16)f.y};
        wv[k / 2 + 1] = (h2f){(_Float16)f.z, (_Float16)f.w};
    }

    if (tid < 2 * HH) ((_Float16*)h_lds)[tid] = (_Float16)0.f;

    const size_t base = (size_t)b * TT * G4 + g;
    float pf[PF];
    #pragma unroll
    for (int u = 0; u < PF; ++u) {
        int tau = dir ? (TT - 1 - u) : u;
        pf[u] = pre[base + (size_t)tau * G4];
    }

    float c = 0.f;
    const float ASIG = -1.4426950408889634f;  // -log2(e)
    const float ATAN =  2.8853900817779268f;  // 2*log2(e)
    const float aa = (q == 2) ? ATAN : ASIG;

    __syncthreads();

    for (int s0 = 0; s0 < TT; s0 += PF) {
        #pragma unroll
        for (int u = 0; u < PF; ++u) {
            const int s = s0 + u;
            const int cur = u & 1;            // parity(s) == parity(u)

            float a0 = 0.f, a1 = 0.f, a2 = 0.f, a3 = 0.f;
            #pragma unroll
            for (int k = 0; k < HH; k += 8) {
                union { h8f v; h2f p[4]; } hu;
                hu.v = *(const h8f*)&h_lds[cur][k];   // uniform broadcast b128
                a0 = fdot2_(wv[k / 2 + 0], hu.p[0], a0);
                a1 = fdot2_(wv[k / 2 + 1], hu.p[1], a1);
                a2 = fdot2_(wv[k / 2 + 2], hu.p[2], a2);
                a3 = fdot2_(wv[k / 2 + 3], hu.p[3], a3);
            }
            float gate = pf[u] + ((a0 + a1) + (a2 + a3));

            // ring refill (clamped, branch-free)
            {
                int sn = s + PF;
                int taun = dir ? (TT - 1 - sn) : sn;
                taun = taun < 0 ? 0 : (taun > TT - 1 ? TT - 1 : taun);
                pf[u] = pre[base + (size_t)taun * G4];
            }

            // own-gate activation: sigmoid (i,f,o) / tanh (g)
            float e = __builtin_amdgcn_exp2f(aa * gate);
            float r = __builtin_amdgcn_rcpf(1.f + e);
            float v = (q == 2) ? (1.f - 2.f * r) : r;

            // quad rotations: at q==0 lanes, r1=f-sig, r2=g-tanh, r3=o-sig
            int vi = __float_as_int(v);
            float sf = __int_as_float(__builtin_amdgcn_update_dpp(vi, vi, 0x39, 0xF, 0xF, false)); // [1,2,3,0]
            float tg = __int_as_float(__builtin_amdgcn_update_dpp(vi, vi, 0x4E, 0xF, 0xF, false)); // [2,3,0,1]
            float so = __int_as_float(__builtin_amdgcn_update_dpp(vi, vi, 0x93, 0xF, 0xF, false)); // [3,0,1,2]

            if (q == 0) {
                c = fmaf(sf, c, v * tg);
                float e2 = __builtin_amdgcn_exp2f(ATAN * c);
                float r2 = __builtin_amdgcn_rcpf(1.f + e2);
                float h  = so * (1.f - 2.f * r2);
                h_lds[cur ^ 1][j] = (_Float16)h;
                int tau = dir ? (TT - 1 - s) : s;
                out[((size_t)b * TT + tau) * (2 * HH) + dir * HH + j] = h;
            }
            __syncthreads();
        }
    }
}

// ---------------- FC ----------------
__global__ __launch_bounds__(256) void fc_kernel(
    const float* __restrict__ h2, const float* __restrict__ w_fc,
    const float* __restrict__ b_fc, float* __restrict__ out)
{
    int idx = blockIdx.x * 256 + threadIdx.x;
    int m = idx >> 6;
    int n = idx & 63;
    const float4* hr = (const float4*)(h2 + (size_t)m * 256);
    const float4* wr = (const float4*)(w_fc + (size_t)n * 256);
    float acc = 0.f;
    #pragma unroll 8
    for (int k = 0; k < 64; ++k) {
        float4 a = hr[k];
        float4 wv = wr[k];
        acc += a.x * wv.x + a.y * wv.y + a.z * wv.z + a.w * wv.w;
    }
    out[idx] = acc + b_fc[n];
}

extern "C" void kernel_launch(void* const* d_in, const int* in_sizes, int n_in,
                              void* d_out, int out_size, void* d_ws, size_t ws_size,
                              hipStream_t stream) {
    const float* x        = (const float*)d_in[0];
    const float* w_ih_l0  = (const float*)d_in[1];
    const float* w_hh_l0  = (const float*)d_in[2];
    const float* b_ih_l0  = (const float*)d_in[3];
    const float* b_hh_l0  = (const float*)d_in[4];
    const float* w_ih_l0r = (const float*)d_in[5];
    const float* w_hh_l0r = (const float*)d_in[6];
    const float* b_ih_l0r = (const float*)d_in[7];
    const float* b_hh_l0r = (const float*)d_in[8];
    const float* w_ih_l1  = (const float*)d_in[9];
    const float* w_hh_l1  = (const float*)d_in[10];
    const float* b_ih_l1  = (const float*)d_in[11];
    const float* b_hh_l1  = (const float*)d_in[12];
    const float* w_ih_l1r = (const float*)d_in[13];
    const float* w_hh_l1r = (const float*)d_in[14];
    const float* b_ih_l1r = (const float*)d_in[15];
    const float* b_hh_l1r = (const float*)d_in[16];
    const float* w_fc     = (const float*)d_in[17];
    const float* b_fc     = (const float*)d_in[18];

    float* ws    = (float*)d_ws;
    float* pre_f = ws;                       // 16,777,216 floats
    float* pre_b = ws + 16777216;            // 16,777,216 floats
    float* out0  = ws + 2 * 16777216;        // 8,388,608 floats
    float* out1  = out0 + 8388608;           // 8,388,608 floats

    // A hi/lo aliases (lifetimes verified):
    //  x split lives in out0's region, consumed by gemm l0 BEFORE scan l0 writes out0.
    //  out0 split lives in out1's region (exact fit), consumed by gemm l1 BEFORE
    //  scan l1 writes out1.
    short* xhi  = (short*)out0;              // 2,097,152 shorts
    short* xlo  = xhi + 2097152;
    short* a1hi = (short*)out1;              // 8,388,608 shorts
    short* a1lo = a1hi + 8388608;

    dim3 gg(256, 4);  // M/128 x 512/128

    // Layer 0
    convert_hilo<<<2048, 256, 0, stream>>>((const float4*)x, (s16x4*)xhi, (s16x4*)xlo, 524288);
    gemm_mfma2<64><<<gg, 256, 0, stream>>>(xhi, xlo, w_ih_l0,  b_ih_l0,  b_hh_l0,  pre_f);
    gemm_mfma2<64><<<gg, 256, 0, stream>>>(xhi, xlo, w_ih_l0r, b_ih_l0r, b_hh_l0r, pre_b);
    lstm_scan_v6<<<128, 512, 0, stream>>>(pre_f, pre_b, w_hh_l0, w_hh_l0r, out0);

    // Layer 1
    convert_hilo<<<2048, 256, 0, stream>>>((const float4*)out0, (s16x4*)a1hi, (s16x4*)a1lo, 2097152);
    gemm_mfma2<256><<<gg, 256, 0, stream>>>(a1hi, a1lo, w_ih_l1,  b_ih_l1,  b_hh_l1,  pre_f);
    gemm_mfma2<256><<<gg, 256, 0, stream>>>(a1hi, a1lo, w_ih_l1r, b_ih_l1r, b_hh_l1r, pre_b);
    lstm_scan_v6<<<128, 512, 0, stream>>>(pre_f, pre_b, w_hh_l1, w_hh_l1r, out1);

    // FC
    fc_kernel<<<(BB * TT * 64) / 256, 256, 0, stream>>>(out1, w_fc, b_fc, (float*)d_out);
}

// Round 7
// 775.922 us; speedup vs baseline: 2.8583x; 1.2475x over previous
//
#include <hip/hip_runtime.h>

#define TT 512   // sequence length
#define BB 64    // batch
#define HH 128   // hidden
#define G4 512   // 4*H
#define PF 8     // prefetch ring depth (even, divides TT)

typedef short bf16x8 __attribute__((ext_vector_type(8)));
typedef short s16x4  __attribute__((ext_vector_type(4)));
typedef float f32x4  __attribute__((ext_vector_type(4)));
typedef _Float16 h2f __attribute__((ext_vector_type(2)));
typedef _Float16 h8f __attribute__((ext_vector_type(8)));

__device__ __forceinline__ unsigned short f2bf(float x) {
    unsigned u = __float_as_uint(x);
    u += 0x7fff + ((u >> 16) & 1);           // RNE
    return (unsigned short)(u >> 16);
}
__device__ __forceinline__ float bf2f(unsigned short h) {
    return __uint_as_float(((unsigned)h) << 16);
}
__device__ __forceinline__ float fdot2_(h2f a, h2f b, float c) {
#if __has_builtin(__builtin_amdgcn_fdot2)
    return __builtin_amdgcn_fdot2(a, b, c, false);
#else
    return c + (float)a[0] * (float)b[0] + (float)a[1] * (float)b[1];
#endif
}

// ---------------- fp32 -> bf16 hi/lo split (memory-bound) ----------------
__global__ __launch_bounds__(256) void convert_hilo(
    const float4* __restrict__ src, s16x4* __restrict__ hi,
    s16x4* __restrict__ lo, int n4)
{
    for (int i = blockIdx.x * 256 + threadIdx.x; i < n4; i += gridDim.x * 256) {
        float4 f = src[i];
        float fa[4] = {f.x, f.y, f.z, f.w};
        s16x4 h, l;
        #pragma unroll
        for (int e = 0; e < 4; ++e) {
            unsigned short hh = f2bf(fa[e]);
            h[e] = (short)hh;
            l[e] = (short)f2bf(fa[e] - bf2f(hh));
        }
        hi[i] = h;
        lo[i] = l;
    }
}

// ---------------- MFMA pre-GEMM v2 (unchanged from R6, passing) ----------------
template<int K>
__global__ __launch_bounds__(256) void gemm_mfma2(
    const short* __restrict__ Ahi, const short* __restrict__ Alo,
    const float* __restrict__ W,
    const float* __restrict__ b0, const float* __restrict__ b1,
    float* __restrict__ C)
{
    constexpr int NC  = K / 32;
    constexpr int LDA = 40;                  // shorts per staged row (32 + 8 pad)
    __shared__ short Ahi_s[128 * LDA], Alo_s[128 * LDA];
    __shared__ short Whi_s[128 * LDA], Wlo_s[128 * LDA];

    const int bm  = blockIdx.x * 128;
    const int bn  = blockIdx.y * 128;
    const int tid = threadIdx.x;
    const int wv  = tid >> 6;
    const int l   = tid & 63;
    const int jl  = l & 15;
    const int rg  = l >> 4;
    const int wr  = wv >> 1;
    const int wc  = wv & 1;

    const int sr = tid >> 1;
    const int sc = (tid & 1) * 16;

    const short* Aph = Ahi + (size_t)(bm + sr) * K + sc;
    const short* Apl = Alo + (size_t)(bm + sr) * K + sc;
    const float* Wp  = W   + (size_t)(bn + sr) * K + sc;

    f32x4 acc[4][4];
    #pragma unroll
    for (int i = 0; i < 4; ++i)
        #pragma unroll
        for (int j = 0; j < 4; ++j)
            acc[i][j] = (f32x4){0.f, 0.f, 0.f, 0.f};

    bf16x8 pah[2], pal[2];
    float4 pw[4];
    pah[0] = *(const bf16x8*)(Aph);
    pah[1] = *(const bf16x8*)(Aph + 8);
    pal[0] = *(const bf16x8*)(Apl);
    pal[1] = *(const bf16x8*)(Apl + 8);
    #pragma unroll
    for (int q = 0; q < 4; ++q) pw[q] = *(const float4*)(Wp + q * 4);

    #pragma unroll 1
    for (int c = 0; c < NC; ++c) {
        __syncthreads();
        {
            int off = sr * LDA + sc;
            *(bf16x8*)&Ahi_s[off]     = pah[0];
            *(bf16x8*)&Ahi_s[off + 8] = pah[1];
            *(bf16x8*)&Alo_s[off]     = pal[0];
            *(bf16x8*)&Alo_s[off + 8] = pal[1];
            #pragma unroll
            for (int q = 0; q < 4; ++q) {
                float fw[4] = {pw[q].x, pw[q].y, pw[q].z, pw[q].w};
                s16x4 h, lo4;
                #pragma unroll
                for (int e = 0; e < 4; ++e) {
                    unsigned short hh = f2bf(fw[e]);
                    h[e]   = (short)hh;
                    lo4[e] = (short)f2bf(fw[e] - bf2f(hh));
                }
                *(s16x4*)&Whi_s[off + q * 4] = h;
                *(s16x4*)&Wlo_s[off + q * 4] = lo4;
            }
        }
        __syncthreads();
        if (c + 1 < NC) {
            pah[0] = *(const bf16x8*)(Aph + (c + 1) * 32);
            pah[1] = *(const bf16x8*)(Aph + (c + 1) * 32 + 8);
            pal[0] = *(const bf16x8*)(Apl + (c + 1) * 32);
            pal[1] = *(const bf16x8*)(Apl + (c + 1) * 32 + 8);
            #pragma unroll
            for (int q = 0; q < 4; ++q)
                pw[q] = *(const float4*)(Wp + (c + 1) * 32 + q * 4);
        }
        bf16x8 ah[4], al[4], wh[4], wl[4];
        #pragma unroll
        for (int t = 0; t < 4; ++t) {
            int ra = (wr * 64 + t * 16 + jl) * LDA + rg * 8;
            ah[t] = *(const bf16x8*)&Ahi_s[ra];
            al[t] = *(const bf16x8*)&Alo_s[ra];
            int rw = (wc * 64 + t * 16 + jl) * LDA + rg * 8;
            wh[t] = *(const bf16x8*)&Whi_s[rw];
            wl[t] = *(const bf16x8*)&Wlo_s[rw];
        }
        #pragma unroll
        for (int tm = 0; tm < 4; ++tm)
            #pragma unroll
            for (int tn = 0; tn < 4; ++tn) {
                acc[tm][tn] = __builtin_amdgcn_mfma_f32_16x16x32_bf16(ah[tm], wh[tn], acc[tm][tn], 0, 0, 0);
                acc[tm][tn] = __builtin_amdgcn_mfma_f32_16x16x32_bf16(ah[tm], wl[tn], acc[tm][tn], 0, 0, 0);
                acc[tm][tn] = __builtin_amdgcn_mfma_f32_16x16x32_bf16(al[tm], wh[tn], acc[tm][tn], 0, 0, 0);
            }
    }

    #pragma unroll
    for (int tn = 0; tn < 4; ++tn) {
        int n = bn + wc * 64 + tn * 16 + jl;
        float bias = b0[n] + b1[n];
        #pragma unroll
        for (int tm = 0; tm < 4; ++tm) {
            int m = bm + wr * 64 + tm * 16 + rg * 4;
            #pragma unroll
            for (int r = 0; r < 4; ++r)
                C[(size_t)(m + r) * G4 + n] = acc[tm][tn][r] + bias;
        }
    }
}

// ---------------- scalar LSTM scan v7: v6 + k-split (2 rows/lane, half-k each) ----
// 128 blocks = 2dir x 64batch, 512 thr (8 waves).
// Lane l: q = l&3 (gate), ci = (l>>2)&3, kh = (l>>4)&1 (k-half), g2 = l>>5.
// Wave w covers cells [w*16, w*16+16): jA = w*16+g2*8+ci, jB = jA+4.
// Lane computes partials of rows (q,jA),(q,jB) over k in [kh*64, kh*64+64).
// One ds_swizzle xor16 exchanges the crosswise partial; kh0 lane finishes row A,
// kh1 finishes row B. Quad DPP gathers f,g,o; (q==0) lanes own c for jw.
__global__ __launch_bounds__(512) void lstm_scan_v7(
    const float* __restrict__ pre_f, const float* __restrict__ pre_b,
    const float* __restrict__ whh_f, const float* __restrict__ whh_b,
    float* __restrict__ out)
{
    const int dir = blockIdx.x >> 6;
    const int b   = blockIdx.x & 63;
    const float* __restrict__ pre  = dir ? pre_b : pre_f;
    const float* __restrict__ w_hh = dir ? whh_b : whh_f;

    const int tid = threadIdx.x;
    const int w   = tid >> 6;
    const int l   = tid & 63;
    const int q   = l & 3;
    const int ci  = (l >> 2) & 3;
    const int kh  = (l >> 4) & 1;
    const int g2  = l >> 5;
    const int jA  = w * 16 + g2 * 8 + ci;
    const int jB  = jA + 4;
    const int rA  = q * HH + jA;
    const int rB  = q * HH + jB;
    const int jw  = kh ? jB : jA;           // cell this lane finishes
    const int rS  = kh ? rB : rA;           // row this lane finishes

    __shared__ _Float16 h_lds[2][HH];

    // weights: rows rA,rB over this lane's k-half, packed fp16 (64 dwords)
    h2f wA[32], wB[32];
    #pragma unroll
    for (int k = 0; k < 64; k += 4) {
        float4 fa = *(const float4*)&w_hh[(size_t)rA * HH + kh * 64 + k];
        wA[k / 2]     = (h2f){(_Float16)fa.x, (_Float16)fa.y};
        wA[k / 2 + 1] = (h2f){(_Float16)fa.z, (_Float16)fa.w};
        float4 fb = *(const float4*)&w_hh[(size_t)rB * HH + kh * 64 + k];
        wB[k / 2]     = (h2f){(_Float16)fb.x, (_Float16)fb.y};
        wB[k / 2 + 1] = (h2f){(_Float16)fb.z, (_Float16)fb.w};
    }

    if (tid < 2 * HH) ((_Float16*)h_lds)[tid] = (_Float16)0.f;

    const size_t base = (size_t)b * TT * G4 + rS;
    float pf[PF];
    #pragma unroll
    for (int u = 0; u < PF; ++u) {
        int tau = dir ? (TT - 1 - u) : u;
        pf[u] = pre[base + (size_t)tau * G4];
    }

    float c = 0.f;
    const float ASIG = -1.4426950408889634f;  // -log2(e)
    const float ATAN =  2.8853900817779268f;  // 2*log2(e)
    const float aa = (q == 2) ? ATAN : ASIG;

    __syncthreads();

    for (int s0 = 0; s0 < TT; s0 += PF) {
        #pragma unroll
        for (int u = 0; u < PF; ++u) {
            const int s = s0 + u;
            const int cur = u & 1;            // parity(s) == parity(u)

            // partial dots over own k-half (8 broadcast b128 reads)
            float pa0 = 0.f, pa1 = 0.f, pb0 = 0.f, pb1 = 0.f;
            const _Float16* hb = &h_lds[cur][kh * 64];
            #pragma unroll
            for (int k8 = 0; k8 < 8; ++k8) {
                union { h8f v; h2f p[4]; } hu;
                hu.v = *(const h8f*)&hb[k8 * 8];
                pa0 = fdot2_(wA[k8 * 4 + 0], hu.p[0], pa0);
                pa1 = fdot2_(wA[k8 * 4 + 1], hu.p[1], pa1);
                pa0 = fdot2_(wA[k8 * 4 + 2], hu.p[2], pa0);
                pa1 = fdot2_(wA[k8 * 4 + 3], hu.p[3], pa1);
                pb0 = fdot2_(wB[k8 * 4 + 0], hu.p[0], pb0);
                pb1 = fdot2_(wB[k8 * 4 + 1], hu.p[1], pb1);
                pb0 = fdot2_(wB[k8 * 4 + 2], hu.p[2], pb0);
                pb1 = fdot2_(wB[k8 * 4 + 3], hu.p[3], pb1);
            }
            float pA = pa0 + pa1;
            float pB = pb0 + pb1;

            // crosswise exchange: kh0 keeps A / sends B; kh1 keeps B / sends A
            float own  = kh ? pB : pA;
            float send = kh ? pA : pB;
            float recv = __int_as_float(
                __builtin_amdgcn_ds_swizzle(__float_as_int(send), 0x401F)); // xor 16
            float gate = pf[u] + own + recv;

            // ring refill (clamped, branch-free)
            {
                int sn = s + PF;
                int taun = dir ? (TT - 1 - sn) : sn;
                taun = taun < 0 ? 0 : (taun > TT - 1 ? TT - 1 : taun);
                pf[u] = pre[base + (size_t)taun * G4];
            }

            // own-gate activation: sigmoid (i,f,o) / tanh (g)
            float e = __builtin_amdgcn_exp2f(aa * gate);
            float r = __builtin_amdgcn_rcpf(1.f + e);
            float v = (q == 2) ? (1.f - 2.f * r) : r;

            // quad rotations: at q==0 lanes, sf=f-sig, tg=g-tanh, so=o-sig
            int vi = __float_as_int(v);
            float sf = __int_as_float(__builtin_amdgcn_update_dpp(vi, vi, 0x39, 0xF, 0xF, false));
            float tg = __int_as_float(__builtin_amdgcn_update_dpp(vi, vi, 0x4E, 0xF, 0xF, false));
            float so = __int_as_float(__builtin_amdgcn_update_dpp(vi, vi, 0x93, 0xF, 0xF, false));

            if (q == 0) {
                c = fmaf(sf, c, v * tg);
                float e2 = __builtin_amdgcn_exp2f(ATAN * c);
                float r2 = __builtin_amdgcn_rcpf(1.f + e2);
                float h  = so * (1.f - 2.f * r2);
                h_lds[cur ^ 1][jw] = (_Float16)h;
                int tau = dir ? (TT - 1 - s) : s;
                out[((size_t)b * TT + tau) * (2 * HH) + dir * HH + jw] = h;
            }
            __syncthreads();
        }
    }
}

// ---------------- FC v2: w_fc staged in LDS, h2 wave-uniform reads ----------------
// out[m,n] = b_fc[n] + sum_k h2[m,k]*w_fc[n,k]; M=32768, N=64, K=256.
// 512 blocks x 256 thr; m-tile 64 (4 waves x 16 rows). wsT[k4][n] in LDS (64KB).
__global__ __launch_bounds__(256) void fc_v2(
    const float* __restrict__ h2, const float* __restrict__ w_fc,
    const float* __restrict__ b_fc, float* __restrict__ out)
{
    __shared__ float4 wsT[64][64];          // [k4][n] = w_fc[n][4k4..4k4+3]
    const int tid = threadIdx.x;
    const int bm  = blockIdx.x * 64;
    const int n   = tid & 63;
    const int mg  = tid >> 6;               // wave id -> 16-row group

    // stage w_fc (coalesced global reads; one-time LDS write conflicts OK)
    #pragma unroll
    for (int qq = 0; qq < 16; ++qq) {
        int id = qq * 256 + tid;
        int nn = id >> 6, k4 = id & 63;
        wsT[k4][nn] = *(const float4*)&w_fc[(size_t)nn * 256 + k4 * 4];
    }
    __syncthreads();

    const float bias = b_fc[n];
    const float* hrow = h2 + (size_t)(bm + mg * 16) * 256;

    float acc[16];
    #pragma unroll
    for (int mi = 0; mi < 16; ++mi) acc[mi] = 0.f;

    #pragma unroll 2
    for (int k4 = 0; k4 < 64; ++k4) {
        float4 w4 = wsT[k4][n];             // lanes consecutive: conflict-free
        #pragma unroll
        for (int mi = 0; mi < 16; ++mi) {
            float4 h4 = *(const float4*)(hrow + (size_t)mi * 256 + k4 * 4); // wave-uniform
            acc[mi] = fmaf(h4.x, w4.x, acc[mi]);
            acc[mi] = fmaf(h4.y, w4.y, acc[mi]);
            acc[mi] = fmaf(h4.z, w4.z, acc[mi]);
            acc[mi] = fmaf(h4.w, w4.w, acc[mi]);
        }
    }
    #pragma unroll
    for (int mi = 0; mi < 16; ++mi)
        out[(size_t)(bm + mg * 16 + mi) * 64 + n] = acc[mi] + bias;
}

extern "C" void kernel_launch(void* const* d_in, const int* in_sizes, int n_in,
                              void* d_out, int out_size, void* d_ws, size_t ws_size,
                              hipStream_t stream) {
    const float* x        = (const float*)d_in[0];
    const float* w_ih_l0  = (const float*)d_in[1];
    const float* w_hh_l0  = (const float*)d_in[2];
    const float* b_ih_l0  = (const float*)d_in[3];
    const float* b_hh_l0  = (const float*)d_in[4];
    const float* w_ih_l0r = (const float*)d_in[5];
    const float* w_hh_l0r = (const float*)d_in[6];
    const float* b_ih_l0r = (const float*)d_in[7];
    const float* b_hh_l0r = (const float*)d_in[8];
    const float* w_ih_l1  = (const float*)d_in[9];
    const float* w_hh_l1  = (const float*)d_in[10];
    const float* b_ih_l1  = (const float*)d_in[11];
    const float* b_hh_l1  = (const float*)d_in[12];
    const float* w_ih_l1r = (const float*)d_in[13];
    const float* w_hh_l1r = (const float*)d_in[14];
    const float* b_ih_l1r = (const float*)d_in[15];
    const float* b_hh_l1r = (const float*)d_in[16];
    const float* w_fc     = (const float*)d_in[17];
    const float* b_fc     = (const float*)d_in[18];

    float* ws    = (float*)d_ws;
    float* pre_f = ws;                       // 16,777,216 floats
    float* pre_b = ws + 16777216;            // 16,777,216 floats
    float* out0  = ws + 2 * 16777216;        // 8,388,608 floats
    float* out1  = out0 + 8388608;           // 8,388,608 floats

    // A hi/lo aliases (lifetimes verified in R6):
    short* xhi  = (short*)out0;
    short* xlo  = xhi + 2097152;
    short* a1hi = (short*)out1;
    short* a1lo = a1hi + 8388608;

    dim3 gg(256, 4);  // M/128 x 512/128

    // Layer 0
    convert_hilo<<<2048, 256, 0, stream>>>((const float4*)x, (s16x4*)xhi, (s16x4*)xlo, 524288);
    gemm_mfma2<64><<<gg, 256, 0, stream>>>(xhi, xlo, w_ih_l0,  b_ih_l0,  b_hh_l0,  pre_f);
    gemm_mfma2<64><<<gg, 256, 0, stream>>>(xhi, xlo, w_ih_l0r, b_ih_l0r, b_hh_l0r, pre_b);
    lstm_scan_v7<<<128, 512, 0, stream>>>(pre_f, pre_b, w_hh_l0, w_hh_l0r, out0);

    // Layer 1
    convert_hilo<<<2048, 256, 0, stream>>>((const float4*)out0, (s16x4*)a1hi, (s16x4*)a1lo, 2097152);
    gemm_mfma2<256><<<gg, 256, 0, stream>>>(a1hi, a1lo, w_ih_l1,  b_ih_l1,  b_hh_l1,  pre_f);
    gemm_mfma2<256><<<gg, 256, 0, stream>>>(a1hi, a1lo, w_ih_l1r, b_ih_l1r, b_hh_l1r, pre_b);
    lstm_scan_v7<<<128, 512, 0, stream>>>(pre_f, pre_b, w_hh_l1, w_hh_l1r, out1);

    // FC
    fc_v2<<<512, 256, 0, stream>>>(out1, w_fc, b_fc, (float*)d_out);
}